// Round 4
// baseline (288.210 us; speedup 1.0000x reference)
//
#include <hip/hip_runtime.h>
#include <math.h>

#ifndef __has_builtin
#define __has_builtin(x) 0
#endif

__device__ __forceinline__ float fast_exp2(float v) {
#if __has_builtin(__builtin_amdgcn_exp2f)
    return __builtin_amdgcn_exp2f(v);   // v_exp_f32 (base-2), ~1 ulp
#else
    return exp2f(v);
#endif
}

constexpr int R = 20;   // reads per site
constexpr int C = 32;   // channels
constexpr int B = 32;   // bins

// One thread per (site, channel); lane = channel -> every load/store instr is
// two 128B-contiguous segments per wave64 (2 sites). Fully coalesced; all
// load/store offsets fit the 13-bit signed immediate (max 3968B).
//
// KDE factorization (bin centers b/31, sigma^2 = 0.01):
//   exp(-50(x - b/31)^2) = 2^{-Kx^2} * (2^{A2 x + B0})^b * 2^{-(K/961) b(b-1)}
//   K = 50*log2(e), A2 = 2K/31, B0 = -K/961.
// Bins-OUTER loop: per-read state P_r (value) and M_r (step) live in regs;
// each bin does sum(P_r) -> scale -> STORE, then P_r *= M_r. Stores stream
// through the whole wave lifetime instead of bursting in an epilogue, and
// register pressure drops (no acc[32]) -> 8 waves/SIMD.
__global__ __launch_bounds__(256, 8) void kde_kernel(const float* __restrict__ x,
                                                     float* __restrict__ out,
                                                     int nsites) {
    int t = blockIdx.x * blockDim.x + threadIdx.x;
    int c = t & (C - 1);
    int n = t >> 5;
    if (n >= nsites) return;

    const float K  = 72.13475204444817f;    // 50 * log2(e)
    const float A2 = 4.6538549706095594f;   // 2K/31
    const float B0 = -0.07506217694531545f; // -K/961

    const float* xp = x + (size_t)n * (R * C) + c;

    // prefetch all 20 reads (loads in flight together)
    float xv[R];
#pragma unroll
    for (int r = 0; r < R; ++r) xv[r] = xp[(size_t)r * C];

    // per-read value / step-multiplier state (xv regs are reused by these)
    float P[R], M[R];
#pragma unroll
    for (int r = 0; r < R; ++r) {
        float v = xv[r];
        P[r] = fast_exp2(v * v * -K);        // 2^{-K x^2} = exp(-50 x^2)
        M[r] = fast_exp2(fmaf(v, A2, B0));   // 2^{A2 x + B0}
    }

    float* op = out + (size_t)n * (B * C) + c;
#pragma unroll
    for (int b = 0; b < B; ++b) {
        // two independent partial-sum chains (break the serial add dep)
        float s0 = 0.0f, s1 = 0.0f;
#pragma unroll
        for (int r = 0; r < R; r += 2) {
            s0 += P[r];
            s1 += P[r + 1];
            P[r]     *= M[r];
            P[r + 1] *= M[r + 1];
        }
        // cb = (coef/R) * 2^{-(K/961) b(b-1)}  -- compile-time constant
        const float cb = (float)(0.19947114020071635 *
                                 exp2(-0.07506217694531545 * (double)(b * (b - 1))));
        op[(size_t)b * C] = (s0 + s1) * cb;   // streaming store
    }
}

extern "C" void kernel_launch(void* const* d_in, const int* in_sizes, int n_in,
                              void* d_out, int out_size, void* d_ws, size_t ws_size,
                              hipStream_t stream) {
    const float* x = (const float*)d_in[0];
    float* out = (float*)d_out;
    int nsites = in_sizes[0] / (R * C);          // 131072
    int total = nsites * C;                      // one thread per (site, channel)
    int block = 256;
    int grid = (total + block - 1) / block;
    hipLaunchKernelGGL(kde_kernel, dim3(grid), dim3(block), 0, stream, x, out, nsites);
}

// Round 5
// 164.742 us; speedup vs baseline: 1.7495x; 1.7495x over previous
//
#include <hip/hip_runtime.h>
#include <math.h>

#ifndef __has_builtin
#define __has_builtin(x) 0
#endif

__device__ __forceinline__ float fast_exp2(float v) {
#if __has_builtin(__builtin_amdgcn_exp2f)
    return __builtin_amdgcn_exp2f(v);   // v_exp_f32 (base-2), ~1 ulp
#else
    return exp2f(v);
#endif
}

constexpr int R = 20;   // reads per site
constexpr int C = 32;   // channels
constexpr int B = 32;   // bins

// One thread per (site, channel); lane = channel -> every load/store instr is
// two 128B-contiguous segments per wave64 (2 sites). Fully coalesced.
//
// Structure = round-3 winner (bins-inner, acc[32], 170 us), reverted from the
// bins-outer experiment (VGPR spill at launch_bounds(256,8) -> 288 us).
//
// KDE factorization (bin centers b/31, sigma^2 = 0.01):
//   exp(-50(x - b/31)^2) = 2^{-Kx^2} * (2^{A2 x + B0})^b * 2^{-(K/961) b(b-1)}
//   K = 50*log2(e), A2 = 2K/31, B0 = -K/961.
// Inner loop: acc[b] += P; P *= m0  (2 VALU ops/bin). Data-independent
// factor folded into the per-bin epilogue constant.
//
// NEW this round: non-temporal loads/stores. Input is read exactly once,
// output written exactly once -- `nt` hints keep the 872 MB stream from
// allocating in L1/L2/L3 for zero reuse.
__global__ __launch_bounds__(256, 6) void kde_kernel(const float* __restrict__ x,
                                                     float* __restrict__ out,
                                                     int nsites) {
    int t = blockIdx.x * blockDim.x + threadIdx.x;
    int c = t & (C - 1);
    int n = t >> 5;
    if (n >= nsites) return;

    const float K  = 72.13475204444817f;    // 50 * log2(e)
    const float A2 = 4.6538549706095594f;   // 2K/31
    const float B0 = -0.07506217694531545f; // -K/961

    const float* xp = x + (size_t)n * (R * C) + c;

    // prefetch: all 20 loads in flight before compute (non-temporal)
    float xv[R];
#pragma unroll
    for (int r = 0; r < R; ++r) xv[r] = __builtin_nontemporal_load(&xp[(size_t)r * C]);

    float acc[B];
#pragma unroll
    for (int b = 0; b < B; ++b) acc[b] = 0.0f;

#pragma unroll
    for (int r = 0; r < R; ++r) {
        float v = xv[r];
        float P  = fast_exp2(v * v * -K);          // w0 = exp(-50 x^2)
        float m0 = fast_exp2(fmaf(v, A2, B0));     // per-bin step multiplier
#pragma unroll
        for (int b = 0; b < B; ++b) {
            acc[b] += P;       // P == w0 * m0^b
            P *= m0;
        }
    }

    // epilogue: out[b] = acc[b] * (coef/R) * 2^{-(K/961) b(b-1)}
    float* op = out + (size_t)n * (B * C) + c;
#pragma unroll
    for (int b = 0; b < B; ++b) {
        const float cb = (float)(0.19947114020071635 *
                                 exp2(-0.07506217694531545 * (double)(b * (b - 1))));
        __builtin_nontemporal_store(acc[b] * cb, &op[(size_t)b * C]);
    }
}

extern "C" void kernel_launch(void* const* d_in, const int* in_sizes, int n_in,
                              void* d_out, int out_size, void* d_ws, size_t ws_size,
                              hipStream_t stream) {
    const float* x = (const float*)d_in[0];
    float* out = (float*)d_out;
    int nsites = in_sizes[0] / (R * C);          // 131072
    int total = nsites * C;                      // one thread per (site, channel)
    int block = 256;
    int grid = (total + block - 1) / block;
    hipLaunchKernelGGL(kde_kernel, dim3(grid), dim3(block), 0, stream, x, out, nsites);
}